// Round 2
// baseline (107.948 us; speedup 1.0000x reference)
//
#include <hip/hip_runtime.h>

#define N_IN 59
#define N_VALUES 12
#define BLOCK 256

__global__ __launch_bounds__(BLOCK, 2) void value_model_kernel(
    const float* __restrict__ act,    // [B, 59]
    const int*   __restrict__ cards,  // [B, 4, 3] int32
    const float* __restrict__ W,      // [12, 59]
    const float* __restrict__ bias,   // [12]
    float* __restrict__ out,          // [B, 4]
    int B)
{
    __shared__ float actLds[BLOCK * N_IN];      // 60416 B, row stride 59 (odd -> conflict-free)
    __shared__ float WtLds[N_IN * N_VALUES];    // [59][12] transposed W, 2832 B, 16B-aligned rows
    __shared__ float fvLds[N_VALUES][BLOCK];    // 12288 B, bank = tid%32 -> conflict-free gather

    const int tid = threadIdx.x;
    const long rowBase = (long)blockIdx.x * BLOCK;
    const long rowsLeft = (long)B - rowBase;
    const int rows = rowsLeft < BLOCK ? (int)rowsLeft : BLOCK;
    const int validFloats = rows * N_IN;

    // Stage W transposed: WtLds[j*12 + v] = W[v*59 + j]  (708 floats)
    for (int i = tid; i < N_IN * N_VALUES; i += BLOCK) {
        int v = i / N_IN;
        int j = i - v * N_IN;
        WtLds[j * N_VALUES + v] = W[i];
    }

    // Stage act tile with coalesced float4 loads (tile base is 16B-aligned:
    // blockIdx*256*59*4 = blockIdx*60416, 60416 % 16 == 0)
    {
        const float* srcf = act + rowBase * N_IN;
        const float4* src4 = (const float4*)srcf;
        float4* dst4 = (float4*)actLds;
        const int nv4 = validFloats >> 2;
        for (int i = tid; i < nv4; i += BLOCK) dst4[i] = src4[i];
        for (int i = (nv4 << 2) + tid; i < validFloats; i += BLOCK)
            actLds[i] = srcf[i];
    }
    __syncthreads();

    const long row = rowBase + tid;
    if (row < B) {
        float acc[N_VALUES];
        #pragma unroll
        for (int v = 0; v < N_VALUES; ++v) acc[v] = bias[v];

        const float* arow = actLds + tid * N_IN;
        const float4* wt4 = (const float4*)WtLds;   // [59][3] float4, uniform addr -> broadcast
        #pragma unroll
        for (int j = 0; j < N_IN; ++j) {
            float x = arow[j];
            float4 w0 = wt4[j * 3 + 0];
            float4 w1 = wt4[j * 3 + 1];
            float4 w2 = wt4[j * 3 + 2];
            acc[0]  = fmaf(x, w0.x, acc[0]);
            acc[1]  = fmaf(x, w0.y, acc[1]);
            acc[2]  = fmaf(x, w0.z, acc[2]);
            acc[3]  = fmaf(x, w0.w, acc[3]);
            acc[4]  = fmaf(x, w1.x, acc[4]);
            acc[5]  = fmaf(x, w1.y, acc[5]);
            acc[6]  = fmaf(x, w1.z, acc[6]);
            acc[7]  = fmaf(x, w1.w, acc[7]);
            acc[8]  = fmaf(x, w2.x, acc[8]);
            acc[9]  = fmaf(x, w2.y, acc[9]);
            acc[10] = fmaf(x, w2.z, acc[10]);
            acc[11] = fmaf(x, w2.w, acc[11]);
        }

        // Stage feature values for runtime-indexed gather (avoids scratch spill)
        #pragma unroll
        for (int v = 0; v < N_VALUES; ++v) fvLds[v][tid] = acc[v];
        // each thread reads only its own column -> no barrier needed

        const int4* cp = (const int4*)(cards + row * 12);
        int4 c0 = cp[0];
        int4 c1 = cp[1];
        int4 c2 = cp[2];

        float4 o;
        o.x = fvLds[c0.x][tid] + fvLds[c0.y][tid] + fvLds[c0.z][tid];
        o.y = fvLds[c0.w][tid] + fvLds[c1.x][tid] + fvLds[c1.y][tid];
        o.z = fvLds[c1.z][tid] + fvLds[c1.w][tid] + fvLds[c2.x][tid];
        o.w = fvLds[c2.y][tid] + fvLds[c2.z][tid] + fvLds[c2.w][tid];

        *(float4*)(out + row * 4) = o;
    }
}

extern "C" void kernel_launch(void* const* d_in, const int* in_sizes, int n_in,
                              void* d_out, int out_size, void* d_ws, size_t ws_size,
                              hipStream_t stream) {
    const float* act   = (const float*)d_in[0];
    const int*   cards = (const int*)d_in[1];
    const float* W     = (const float*)d_in[2];
    const float* bias  = (const float*)d_in[3];
    float* out = (float*)d_out;

    const int B = in_sizes[0] / N_IN;  // 1,000,000
    const int grid = (B + BLOCK - 1) / BLOCK;
    value_model_kernel<<<grid, BLOCK, 0, stream>>>(act, cards, W, bias, out, B);
}